// Round 18
// baseline (167.897 us; speedup 1.0000x reference)
//
#include <hip/hip_runtime.h>
#include <math.h>

#define N_EL    16
#define N_NUC   4
#define N_FEATS 32
#define N_PAIRS 184
#define HIDDEN  64
#define TB      32           // batch elements per block (one M-tile)
#define BLOCK   256
#define H1LD    68           // h1 stride in tail kernel
#define WS_DIST_OFF 393216                     // dists at 384 KB
#define WS_PART_OFF (393216 + 24117248)        // partials after 24 MB of dists

typedef int   intx8    __attribute__((ext_vector_type(8)));
typedef float floatx16 __attribute__((ext_vector_type(16)));

__device__ __forceinline__ float exp2_raw(float x) {
    float r;
    asm("v_exp_f32 %0, %1" : "=v"(r) : "v"(x));
    return r;
}
__device__ __forceinline__ float log2_raw(float x) {
    float r;
    asm("v_log_f32 %0, %1" : "=v"(r) : "v"(x));
    return r;
}

// triu_indices(16, 1)
__constant__ unsigned char c_I[120] = {
    0,0,0,0,0,0,0,0,0,0,0,0,0,0,0,
    1,1,1,1,1,1,1,1,1,1,1,1,1,1,
    2,2,2,2,2,2,2,2,2,2,2,2,2,
    3,3,3,3,3,3,3,3,3,3,3,3,
    4,4,4,4,4,4,4,4,4,4,4,
    5,5,5,5,5,5,5,5,5,5,
    6,6,6,6,6,6,6,6,6,
    7,7,7,7,7,7,7,7,
    8,8,8,8,8,8,8,
    9,9,9,9,9,9,
    10,10,10,10,10,
    11,11,11,11,
    12,12,12,
    13,13,
    14
};
__constant__ unsigned char c_J[120] = {
    1,2,3,4,5,6,7,8,9,10,11,12,13,14,15,
    2,3,4,5,6,7,8,9,10,11,12,13,14,15,
    3,4,5,6,7,8,9,10,11,12,13,14,15,
    4,5,6,7,8,9,10,11,12,13,14,15,
    5,6,7,8,9,10,11,12,13,14,15,
    6,7,8,9,10,11,12,13,14,15,
    7,8,9,10,11,12,13,14,15,
    8,9,10,11,12,13,14,15,
    9,10,11,12,13,14,15,
    10,11,12,13,14,15,
    11,12,13,14,15,
    12,13,14,15,
    13,14,15,
    14,15,
    15
};

// stable ssp on raw HW transcendentals:
// ssp(x) = max(x,0) + ln2*log2(1 + 2^(-|x|*log2e)) - ln2
__device__ __forceinline__ float ssp(float x) {
    const float z = exp2_raw(-fabsf(x) * 1.4426950408889634f);
    const float w = log2_raw(1.0f + z);
    return fmaxf(x, 0.0f) + fmaf(0.6931471805599453f, w, -0.69314718056f);
}
__device__ __forceinline__ float redg(float v) {
    v += __shfl_xor(v, 1);
    v += __shfl_xor(v, 2);
    v += __shfl_xor(v, 4);
    return v;
}

// ---------------------------------------------------------------------------
// Prep (verified R14-R17): W1 -> fp8 e4m3 (pre-scaled 2^6; MFMA applies 2^-6
// via scale_b) in 32x32x64 B-fragment order.
// ---------------------------------------------------------------------------
__global__ __launch_bounds__(256)
void prep_w1_kernel(const float* __restrict__ W1, intx8* __restrict__ ws)
{
    __shared__ float w[2 * N_FEATS * HIDDEN];
    const int t = blockIdx.x;
    const float* src = W1 + (size_t)(2 * t) * (N_FEATS * HIDDEN);
    for (int k = threadIdx.x; k < 2 * N_FEATS * HIDDEN; k += 256) w[k] = src[k];
    __syncthreads();

    const int tid = threadIdx.x;
    if (tid >= 128) return;
    const int lane = tid & 63;
    const int nh   = tid >> 6;
    const int lh   = lane >> 5;
    const int col  = nh * 32 + (lane & 31);
    const int fb   = lh * 16;
    intx8 frag;
#pragma unroll
    for (int r = 0; r < 8; ++r) {
        const int pair = r >> 2;
        const int fo   = fb + ((r & 3) << 2);
        const float v0 = 64.0f * w[(pair * N_FEATS + fo + 0) * 64 + col];
        const float v1 = 64.0f * w[(pair * N_FEATS + fo + 1) * 64 + col];
        const float v2 = 64.0f * w[(pair * N_FEATS + fo + 2) * 64 + col];
        const float v3 = 64.0f * w[(pair * N_FEATS + fo + 3) * 64 + col];
        int d = __builtin_amdgcn_cvt_pk_fp8_f32(v0, v1, 0, false);
        d     = __builtin_amdgcn_cvt_pk_fp8_f32(v2, v3, d, true);
        frag[r] = d;
    }
    ws[(size_t)(t * 2 + nh) * 64 + lane] = frag;
}

// ---------------------------------------------------------------------------
// Dist kernel (R16): all 184 distances per element -> global dw in the exact
// layout the gemm reads: dw[b*5888 + p*32 + el].
// ---------------------------------------------------------------------------
__global__ __launch_bounds__(256)
void dist_kernel(const float* __restrict__ rs,
                 const float* __restrict__ coords,
                 float* __restrict__ dw)
{
    __shared__ float lds_rs[TB * N_EL * 3];   // 6 KB
    const int tid = threadIdx.x;
    {
        const float* rs_blk = rs + (size_t)blockIdx.x * (TB * N_EL * 3);
        for (int k = tid; k < TB * N_EL * 3; k += 256) lds_rs[k] = rs_blk[k];
    }
    __syncthreads();

    const int el = tid & 31, g = tid >> 5;
    const float* myrs = lds_rs + el * (N_EL * 3);
    float* base = dw + (size_t)blockIdx.x * (N_PAIRS * 32) + el;
#pragma unroll
    for (int i = 0; i < 23; ++i) {
        const int p = g + 8 * i;
        float dx, dy, dz;
        if (p < 64) {
            const int e = p >> 2, n = p & 3;
            dx = myrs[e * 3 + 0] - coords[n * 3 + 0];
            dy = myrs[e * 3 + 1] - coords[n * 3 + 1];
            dz = myrs[e * 3 + 2] - coords[n * 3 + 2];
        } else {
            const int q  = p - 64;
            const int ei = 3 * (int)c_I[q], ej = 3 * (int)c_J[q];
            dx = myrs[ei + 0] - myrs[ej + 0];
            dy = myrs[ei + 1] - myrs[ej + 1];
            dz = myrs[ei + 2] - myrs[ej + 2];
        }
        base[p * 32] = sqrtf(dx * dx + dy * dy + dz * dz);
    }
}

// ---------------------------------------------------------------------------
// GEMM kernel — zero LDS, zero barriers, now 8-way K-split (R18).
// R17 decode: gemm was GRID-limited at 4 blocks/CU (16 waves). Grid 2048
// (block = M-tile x K-half) -> 8 blocks/CU = 32 waves/CU, the HW max.
// K-half 0 = tiles 0..47 (12/wave); K-half 1 = tiles 48..91 (11/wave).
// Single rolling prefetch (R10/R11: register moves are not the wall).
// ---------------------------------------------------------------------------
__global__ __launch_bounds__(BLOCK, 4)
void wfnet_gemm(const float* __restrict__ dw,
                const intx8* __restrict__ ws,
                float* __restrict__ partials)
{
    const int tid  = threadIdx.x;
    const int wave = tid >> 6;
    const int lane = tid & 63;
    const int m    = lane & 31;
    const int lh   = lane >> 5;
    const int mt   = blockIdx.x >> 1;     // M-tile (batch/32)
    const int s    = blockIdx.x & 1;      // K-half
    const int t0   = s ? (48 + wave * 11) : (wave * 12);
    const int nt   = s ? 11 : 12;

    const int f0 = lh * 16;
#define MKC(P, FF) float P##1, P##0; { \
    const float fq = (float)(FF) * (1.0f / 31.0f); \
    const float mu = 10.0f * fq * fq; \
    const float is = 7.0f / (1.0f + 10.0f * fq); \
    P##1 = is * 1.2011224087864498f; \
    P##0 = -mu * P##1; }
    MKC(F0_,  f0 + 0)  MKC(F1_,  f0 + 1)  MKC(F2_,  f0 + 2)  MKC(F3_,  f0 + 3)
    MKC(F4_,  f0 + 4)  MKC(F5_,  f0 + 5)  MKC(F6_,  f0 + 6)  MKC(F7_,  f0 + 7)
    MKC(F8_,  f0 + 8)  MKC(F9_,  f0 + 9)  MKC(F10_, f0 + 10) MKC(F11_, f0 + 11)
    MKC(F12_, f0 + 12) MKC(F13_, f0 + 13) MKC(F14_, f0 + 14) MKC(F15_, f0 + 15)
#undef MKC

    floatx16 accA = {};
    floatx16 accB = {};
    const intx8* wq = ws + ((size_t)t0 * 128 + lane);
    const float* dp = dw + (size_t)mt * (N_PAIRS * 32) + t0 * 64 + m;

#define XO(dd, P) ({ const float t_ = fmaf(dd, P##1, P##0); exp2_raw(t_ * -t_); })
#define MKA8(AV, dx0, dx1) \
    intx8 AV; { int dw_; \
    dw_   = __builtin_amdgcn_cvt_pk_fp8_f32(XO(dx0,F0_),  XO(dx0,F1_),  0,  false); \
    AV[0] = __builtin_amdgcn_cvt_pk_fp8_f32(XO(dx0,F2_),  XO(dx0,F3_),  dw_, true); \
    dw_   = __builtin_amdgcn_cvt_pk_fp8_f32(XO(dx0,F4_),  XO(dx0,F5_),  0,  false); \
    AV[1] = __builtin_amdgcn_cvt_pk_fp8_f32(XO(dx0,F6_),  XO(dx0,F7_),  dw_, true); \
    dw_   = __builtin_amdgcn_cvt_pk_fp8_f32(XO(dx0,F8_),  XO(dx0,F9_),  0,  false); \
    AV[2] = __builtin_amdgcn_cvt_pk_fp8_f32(XO(dx0,F10_), XO(dx0,F11_), dw_, true); \
    dw_   = __builtin_amdgcn_cvt_pk_fp8_f32(XO(dx0,F12_), XO(dx0,F13_), 0,  false); \
    AV[3] = __builtin_amdgcn_cvt_pk_fp8_f32(XO(dx0,F14_), XO(dx0,F15_), dw_, true); \
    dw_   = __builtin_amdgcn_cvt_pk_fp8_f32(XO(dx1,F0_),  XO(dx1,F1_),  0,  false); \
    AV[4] = __builtin_amdgcn_cvt_pk_fp8_f32(XO(dx1,F2_),  XO(dx1,F3_),  dw_, true); \
    dw_   = __builtin_amdgcn_cvt_pk_fp8_f32(XO(dx1,F4_),  XO(dx1,F5_),  0,  false); \
    AV[5] = __builtin_amdgcn_cvt_pk_fp8_f32(XO(dx1,F6_),  XO(dx1,F7_),  dw_, true); \
    dw_   = __builtin_amdgcn_cvt_pk_fp8_f32(XO(dx1,F8_),  XO(dx1,F9_),  0,  false); \
    AV[6] = __builtin_amdgcn_cvt_pk_fp8_f32(XO(dx1,F10_), XO(dx1,F11_), dw_, true); \
    dw_   = __builtin_amdgcn_cvt_pk_fp8_f32(XO(dx1,F12_), XO(dx1,F13_), 0,  false); \
    AV[7] = __builtin_amdgcn_cvt_pk_fp8_f32(XO(dx1,F14_), XO(dx1,F15_), dw_, true); }
#define KROUND(AV, Q0, Q1) { \
    accA = __builtin_amdgcn_mfma_scale_f32_32x32x64_f8f6f4( \
               AV, Q0, accA, 0, 0, 0, 0x7F7F7F7F, 0, 0x79797979); \
    accB = __builtin_amdgcn_mfma_scale_f32_32x32x64_f8f6f4( \
               AV, Q1, accB, 0, 0, 0, 0x7F7F7F7F, 0, 0x79797979); }

    intx8 p0 = wq[0], p1 = wq[64];
    float d0 = dp[0], d1 = dp[32];

    for (int t = 0; t < nt - 1; ++t) {
        const intx8 n0 = wq[128], n1 = wq[192];   // next tile's B-frags
        const float e0 = dp[64],  e1 = dp[96];    // next tile's dists
        MKA8(av, d0, d1)
        KROUND(av, p0, p1)
        wq += 128; dp += 64;
        p0 = n0; p1 = n1; d0 = e0; d1 = e1;
    }
    { MKA8(av, d0, d1) KROUND(av, p0, p1) }       // last tile, no prefetch
#undef KROUND
#undef MKA8
#undef XO

    // dump raw partial; slot = blockIdx*4 + wave = mt*8 + s*4 + wave.
    // C/D: col = lane&31 (+32), row el = (rg&3)+8*(rg>>2)+4*lh
    float* pdst = partials + ((size_t)blockIdx.x * 4 + wave) * 2048;
#pragma unroll
    for (int rg = 0; rg < 16; ++rg) {
        const int el = (rg & 3) + 8 * (rg >> 2) + 4 * lh;
        pdst[el * 64 + m]      = accA[rg];
        pdst[el * 64 + 32 + m] = accB[rg];
    }
}

// ---------------------------------------------------------------------------
// Tail: sum 8 partials + b1 + ssp -> h1 (LDS) -> layers 2/3 + asy + output.
// ---------------------------------------------------------------------------
__global__ __launch_bounds__(BLOCK)
void wfnet_tail(const float* __restrict__ rs,
                const float* __restrict__ coords,
                const float* __restrict__ charges,
                const float* __restrict__ partials,
                const float* __restrict__ b1,
                const float* __restrict__ W2,
                const float* __restrict__ b2,
                const float* __restrict__ W3,
                const float* __restrict__ b3,
                float* __restrict__ out)
{
    __shared__ float lds_rs[TB * N_EL * 3];   // 6 KB
    __shared__ float lds_h1[TB * H1LD];       // 8.7 KB

    const int tid = threadIdx.x;
    const int el  = tid >> 3;
    const int g   = tid & 7;
    const int b   = blockIdx.x * TB + el;

    {
        const float* rs_blk = rs + (size_t)blockIdx.x * (TB * N_EL * 3);
        for (int k = tid; k < TB * N_EL * 3; k += BLOCK) lds_rs[k] = rs_blk[k];
    }

    {   // sum 8 partial slots for (el, cols g*8..g*8+7)
        const float* pb = partials + (size_t)blockIdx.x * 16384 + el * 64 + g * 8;
        const float4 ba = ((const float4*)(b1 + g * 8))[0];
        const float4 bb = ((const float4*)(b1 + g * 8))[1];
        float a0 = ba.x, a1 = ba.y, a2 = ba.z, a3 = ba.w;
        float a4 = bb.x, a5 = bb.y, a6 = bb.z, a7 = bb.w;
#pragma unroll
        for (int w = 0; w < 8; ++w) {
            const float4 q0 = ((const float4*)(pb + w * 2048))[0];
            const float4 q1 = ((const float4*)(pb + w * 2048))[1];
            a0 += q0.x; a1 += q0.y; a2 += q0.z; a3 += q0.w;
            a4 += q1.x; a5 += q1.y; a6 += q1.z; a7 += q1.w;
        }
        float* h1w = lds_h1 + el * H1LD + g * 8;
        h1w[0] = ssp(a0); h1w[1] = ssp(a1); h1w[2] = ssp(a2); h1w[3] = ssp(a3);
        h1w[4] = ssp(a4); h1w[5] = ssp(a5); h1w[6] = ssp(a6); h1w[7] = ssp(a7);
    }

    float asy = 0.0f;
    __syncthreads();
    {
        const float* myrs = lds_rs + el * (N_EL * 3);
        const float4 ch = *(const float4*)charges;
#pragma unroll
        for (int i = 0; i < 8; ++i) {
            const int p = g + 8 * i;
            const int e = p >> 2, n = p & 3;
            const float dx = myrs[e * 3 + 0] - coords[n * 3 + 0];
            const float dy = myrs[e * 3 + 1] - coords[n * 3 + 1];
            const float dz = myrs[e * 3 + 2] - coords[n * 3 + 2];
            const float d = sqrtf(dx * dx + dy * dy + dz * dz);
            const float Z = (n < 2) ? ((n == 0) ? ch.x : ch.y)
                                    : ((n == 2) ? ch.z : ch.w);
            asy += (Z * d + d * d) / (1.0f + d);   // decay = sqrt(2*0.5) = 1
        }
    }
    asy = redg(asy);

    const float4* __restrict__ W2v = (const float4*)W2;
    const float4* __restrict__ b2v = (const float4*)b2;
    const int wbi = g * 2;
    const float4 b2a = b2v[wbi], b2b = b2v[wbi + 1];
    float s0 = b2a.x, s1 = b2a.y, s2 = b2a.z, s3 = b2a.w;
    float s4 = b2b.x, s5 = b2b.y, s6 = b2b.z, s7 = b2b.w;

    const float* __restrict__ h1row = lds_h1 + el * H1LD;
    for (int k = 0; k < HIDDEN; ++k) {
        const float hk  = h1row[k];
        const float4 wa = W2v[k * 16 + wbi];
        const float4 wb = W2v[k * 16 + wbi + 1];
        s0 = fmaf(hk, wa.x, s0); s1 = fmaf(hk, wa.y, s1);
        s2 = fmaf(hk, wa.z, s2); s3 = fmaf(hk, wa.w, s3);
        s4 = fmaf(hk, wb.x, s4); s5 = fmaf(hk, wb.y, s5);
        s6 = fmaf(hk, wb.z, s6); s7 = fmaf(hk, wb.w, s7);
    }

    const float4* __restrict__ W3v = (const float4*)W3;
    const float4 w3a = W3v[wbi], w3b = W3v[wbi + 1];
    float part = ssp(s0) * w3a.x + ssp(s1) * w3a.y
               + ssp(s2) * w3a.z + ssp(s3) * w3a.w
               + ssp(s4) * w3b.x + ssp(s5) * w3b.y
               + ssp(s6) * w3b.z + ssp(s7) * w3b.w;
    part = redg(part);

    if (g == 0) {
        const float ys = part + b3[0];
        out[b] = __expf(ys) * __expf(-asy);
    }
}

extern "C" void kernel_launch(void* const* d_in, const int* in_sizes, int n_in,
                              void* d_out, int out_size, void* d_ws, size_t ws_size,
                              hipStream_t stream) {
    const float* rs      = (const float*)d_in[0];
    const float* coords  = (const float*)d_in[1];
    const float* charges = (const float*)d_in[2];
    const float* W1      = (const float*)d_in[3];
    const float* b1      = (const float*)d_in[4];
    const float* W2      = (const float*)d_in[5];
    const float* b2      = (const float*)d_in[6];
    const float* W3      = (const float*)d_in[7];
    const float* b3      = (const float*)d_in[8];
    float* out = (float*)d_out;

    const int batch = in_sizes[0] / (N_EL * 3);   // 32768
    intx8* w1f8     = (intx8*)d_ws;                          // 368 KB
    float* dists    = (float*)((char*)d_ws + WS_DIST_OFF);   // 24 MB
    float* partials = (float*)((char*)d_ws + WS_PART_OFF);   // 64 MB

    prep_w1_kernel<<<N_PAIRS / 2, 256, 0, stream>>>(W1, w1f8);
    dist_kernel<<<batch / TB, 256, 0, stream>>>(rs, coords, dists);
    wfnet_gemm<<<2 * (batch / TB), BLOCK, 0, stream>>>(dists, w1f8, partials);
    wfnet_tail<<<batch / TB, BLOCK, 0, stream>>>(rs, coords, charges, partials,
                                                 b1, W2, b2, W3, b3, out);
}

// Round 19
// 163.098 us; speedup vs baseline: 1.0294x; 1.0294x over previous
//
#include <hip/hip_runtime.h>
#include <math.h>

#define N_EL    16
#define N_NUC   4
#define N_FEATS 32
#define N_PAIRS 184
#define HIDDEN  64
#define TB      32           // batch elements per block (one M-tile)
#define BLOCK   256
#define H1LD    68           // h1 stride in tail kernel
#define TPW     23           // K-tiles (2 pairs each) per wave; 4*23*2 = 184
#define WS_DIST_OFF 393216                     // dists at 384 KB
#define WS_PART_OFF (393216 + 24117248)        // partials after 24 MB of dists

typedef int   intx8    __attribute__((ext_vector_type(8)));
typedef float floatx16 __attribute__((ext_vector_type(16)));
typedef __fp16 fp16x2  __attribute__((ext_vector_type(2)));

__device__ __forceinline__ float exp2_raw(float x) {
    float r;
    asm("v_exp_f32 %0, %1" : "=v"(r) : "v"(x));
    return r;
}
__device__ __forceinline__ float log2_raw(float x) {
    float r;
    asm("v_log_f32 %0, %1" : "=v"(r) : "v"(x));
    return r;
}
// unpack one half of an fp16x2 dword (shift = 0 or 16, thread-uniform)
__device__ __forceinline__ float unpk(unsigned u, int shift) {
    unsigned short s = (unsigned short)(u >> shift);
    _Float16 h;
    __builtin_memcpy(&h, &s, 2);
    return (float)h;
}

// triu_indices(16, 1)
__constant__ unsigned char c_I[120] = {
    0,0,0,0,0,0,0,0,0,0,0,0,0,0,0,
    1,1,1,1,1,1,1,1,1,1,1,1,1,1,
    2,2,2,2,2,2,2,2,2,2,2,2,2,
    3,3,3,3,3,3,3,3,3,3,3,3,
    4,4,4,4,4,4,4,4,4,4,4,
    5,5,5,5,5,5,5,5,5,5,
    6,6,6,6,6,6,6,6,6,
    7,7,7,7,7,7,7,7,
    8,8,8,8,8,8,8,
    9,9,9,9,9,9,
    10,10,10,10,10,
    11,11,11,11,
    12,12,12,
    13,13,
    14
};
__constant__ unsigned char c_J[120] = {
    1,2,3,4,5,6,7,8,9,10,11,12,13,14,15,
    2,3,4,5,6,7,8,9,10,11,12,13,14,15,
    3,4,5,6,7,8,9,10,11,12,13,14,15,
    4,5,6,7,8,9,10,11,12,13,14,15,
    5,6,7,8,9,10,11,12,13,14,15,
    6,7,8,9,10,11,12,13,14,15,
    7,8,9,10,11,12,13,14,15,
    8,9,10,11,12,13,14,15,
    9,10,11,12,13,14,15,
    10,11,12,13,14,15,
    11,12,13,14,15,
    12,13,14,15,
    13,14,15,
    14,15,
    15
};

// stable ssp on raw HW transcendentals
__device__ __forceinline__ float ssp(float x) {
    const float z = exp2_raw(-fabsf(x) * 1.4426950408889634f);
    const float w = log2_raw(1.0f + z);
    return fmaxf(x, 0.0f) + fmaf(0.6931471805599453f, w, -0.69314718056f);
}
__device__ __forceinline__ float redg(float v) {
    v += __shfl_xor(v, 1);
    v += __shfl_xor(v, 2);
    v += __shfl_xor(v, 4);
    return v;
}

// ---------------------------------------------------------------------------
// Prep (verified R14-R18): W1 -> fp8 e4m3 (pre-scaled 2^6; MFMA applies 2^-6
// via scale_b) in 32x32x64 B-fragment order.
// ---------------------------------------------------------------------------
__global__ __launch_bounds__(256)
void prep_w1_kernel(const float* __restrict__ W1, intx8* __restrict__ ws)
{
    __shared__ float w[2 * N_FEATS * HIDDEN];
    const int t = blockIdx.x;
    const float* src = W1 + (size_t)(2 * t) * (N_FEATS * HIDDEN);
    for (int k = threadIdx.x; k < 2 * N_FEATS * HIDDEN; k += 256) w[k] = src[k];
    __syncthreads();

    const int tid = threadIdx.x;
    if (tid >= 128) return;
    const int lane = tid & 63;
    const int nh   = tid >> 6;
    const int lh   = lane >> 5;
    const int col  = nh * 32 + (lane & 31);
    const int fb   = lh * 16;
    intx8 frag;
#pragma unroll
    for (int r = 0; r < 8; ++r) {
        const int pair = r >> 2;
        const int fo   = fb + ((r & 3) << 2);
        const float v0 = 64.0f * w[(pair * N_FEATS + fo + 0) * 64 + col];
        const float v1 = 64.0f * w[(pair * N_FEATS + fo + 1) * 64 + col];
        const float v2 = 64.0f * w[(pair * N_FEATS + fo + 2) * 64 + col];
        const float v3 = 64.0f * w[(pair * N_FEATS + fo + 3) * 64 + col];
        int d = __builtin_amdgcn_cvt_pk_fp8_f32(v0, v1, 0, false);
        d     = __builtin_amdgcn_cvt_pk_fp8_f32(v2, v3, d, true);
        frag[r] = d;
    }
    ws[(size_t)(t * 2 + nh) * 64 + lane] = frag;
}

// ---------------------------------------------------------------------------
// Dist kernel (R16): all 184 distances per element -> global dw in the exact
// layout the gemm reads: dw[b*5888 + p*32 + el].
// ---------------------------------------------------------------------------
__global__ __launch_bounds__(256)
void dist_kernel(const float* __restrict__ rs,
                 const float* __restrict__ coords,
                 float* __restrict__ dw)
{
    __shared__ float lds_rs[TB * N_EL * 3];   // 6 KB
    const int tid = threadIdx.x;
    {
        const float* rs_blk = rs + (size_t)blockIdx.x * (TB * N_EL * 3);
        for (int k = tid; k < TB * N_EL * 3; k += 256) lds_rs[k] = rs_blk[k];
    }
    __syncthreads();

    const int el = tid & 31, g = tid >> 5;
    const float* myrs = lds_rs + el * (N_EL * 3);
    float* base = dw + (size_t)blockIdx.x * (N_PAIRS * 32) + el;
#pragma unroll
    for (int i = 0; i < 23; ++i) {
        const int p = g + 8 * i;
        float dx, dy, dz;
        if (p < 64) {
            const int e = p >> 2, n = p & 3;
            dx = myrs[e * 3 + 0] - coords[n * 3 + 0];
            dy = myrs[e * 3 + 1] - coords[n * 3 + 1];
            dz = myrs[e * 3 + 2] - coords[n * 3 + 2];
        } else {
            const int q  = p - 64;
            const int ei = 3 * (int)c_I[q], ej = 3 * (int)c_J[q];
            dx = myrs[ei + 0] - myrs[ej + 0];
            dy = myrs[ei + 1] - myrs[ej + 1];
            dz = myrs[ei + 2] - myrs[ej + 2];
        }
        base[p * 32] = sqrtf(dx * dx + dy * dy + dz * dz);
    }
}

// ---------------------------------------------------------------------------
// GEMM kernel — zero LDS, zero barriers, 4-way K-split (R17 geometry), fp16
// packed partials (R19). R18 decode: the fp32 partials write (64 MB, ~20 us
// of the 46) + tail re-read (~15 us) is the largest attackable term; TLP is
// saturated. Pack (colA, colB) -> one fp16x2 dword: 8 MB total.
// ---------------------------------------------------------------------------
__global__ __launch_bounds__(BLOCK, 4)
void wfnet_gemm(const float* __restrict__ dw,
                const intx8* __restrict__ ws,
                unsigned* __restrict__ partials)
{
    const int tid  = threadIdx.x;
    const int wave = tid >> 6;
    const int lane = tid & 63;
    const int m    = lane & 31;
    const int lh   = lane >> 5;
    const int t0   = wave * TPW;

    const int f0 = lh * 16;
#define MKC(P, FF) float P##1, P##0; { \
    const float fq = (float)(FF) * (1.0f / 31.0f); \
    const float mu = 10.0f * fq * fq; \
    const float is = 7.0f / (1.0f + 10.0f * fq); \
    P##1 = is * 1.2011224087864498f; \
    P##0 = -mu * P##1; }
    MKC(F0_,  f0 + 0)  MKC(F1_,  f0 + 1)  MKC(F2_,  f0 + 2)  MKC(F3_,  f0 + 3)
    MKC(F4_,  f0 + 4)  MKC(F5_,  f0 + 5)  MKC(F6_,  f0 + 6)  MKC(F7_,  f0 + 7)
    MKC(F8_,  f0 + 8)  MKC(F9_,  f0 + 9)  MKC(F10_, f0 + 10) MKC(F11_, f0 + 11)
    MKC(F12_, f0 + 12) MKC(F13_, f0 + 13) MKC(F14_, f0 + 14) MKC(F15_, f0 + 15)
#undef MKC

    floatx16 accA = {};
    floatx16 accB = {};
    const intx8* wq = ws + ((size_t)t0 * 128 + lane);
    const float* dp = dw + (size_t)blockIdx.x * (N_PAIRS * 32) + t0 * 64 + m;

#define XO(dd, P) ({ const float t_ = fmaf(dd, P##1, P##0); exp2_raw(t_ * -t_); })
#define MKA8(AV, dx0, dx1) \
    intx8 AV; { int dw_; \
    dw_   = __builtin_amdgcn_cvt_pk_fp8_f32(XO(dx0,F0_),  XO(dx0,F1_),  0,  false); \
    AV[0] = __builtin_amdgcn_cvt_pk_fp8_f32(XO(dx0,F2_),  XO(dx0,F3_),  dw_, true); \
    dw_   = __builtin_amdgcn_cvt_pk_fp8_f32(XO(dx0,F4_),  XO(dx0,F5_),  0,  false); \
    AV[1] = __builtin_amdgcn_cvt_pk_fp8_f32(XO(dx0,F6_),  XO(dx0,F7_),  dw_, true); \
    dw_   = __builtin_amdgcn_cvt_pk_fp8_f32(XO(dx0,F8_),  XO(dx0,F9_),  0,  false); \
    AV[2] = __builtin_amdgcn_cvt_pk_fp8_f32(XO(dx0,F10_), XO(dx0,F11_), dw_, true); \
    dw_   = __builtin_amdgcn_cvt_pk_fp8_f32(XO(dx0,F12_), XO(dx0,F13_), 0,  false); \
    AV[3] = __builtin_amdgcn_cvt_pk_fp8_f32(XO(dx0,F14_), XO(dx0,F15_), dw_, true); \
    dw_   = __builtin_amdgcn_cvt_pk_fp8_f32(XO(dx1,F0_),  XO(dx1,F1_),  0,  false); \
    AV[4] = __builtin_amdgcn_cvt_pk_fp8_f32(XO(dx1,F2_),  XO(dx1,F3_),  dw_, true); \
    dw_   = __builtin_amdgcn_cvt_pk_fp8_f32(XO(dx1,F4_),  XO(dx1,F5_),  0,  false); \
    AV[5] = __builtin_amdgcn_cvt_pk_fp8_f32(XO(dx1,F6_),  XO(dx1,F7_),  dw_, true); \
    dw_   = __builtin_amdgcn_cvt_pk_fp8_f32(XO(dx1,F8_),  XO(dx1,F9_),  0,  false); \
    AV[6] = __builtin_amdgcn_cvt_pk_fp8_f32(XO(dx1,F10_), XO(dx1,F11_), dw_, true); \
    dw_   = __builtin_amdgcn_cvt_pk_fp8_f32(XO(dx1,F12_), XO(dx1,F13_), 0,  false); \
    AV[7] = __builtin_amdgcn_cvt_pk_fp8_f32(XO(dx1,F14_), XO(dx1,F15_), dw_, true); }
#define KROUND(AV, Q0, Q1) { \
    accA = __builtin_amdgcn_mfma_scale_f32_32x32x64_f8f6f4( \
               AV, Q0, accA, 0, 0, 0, 0x7F7F7F7F, 0, 0x79797979); \
    accB = __builtin_amdgcn_mfma_scale_f32_32x32x64_f8f6f4( \
               AV, Q1, accB, 0, 0, 0, 0x7F7F7F7F, 0, 0x79797979); }

    intx8 p0 = wq[0], p1 = wq[64];
    float d0 = dp[0], d1 = dp[32];

    for (int t = 0; t < TPW - 1; ++t) {
        const intx8 n0 = wq[128], n1 = wq[192];   // next tile's B-frags
        const float e0 = dp[64],  e1 = dp[96];    // next tile's dists
        MKA8(av, d0, d1)
        KROUND(av, p0, p1)
        wq += 128; dp += 64;
        p0 = n0; p1 = n1; d0 = e0; d1 = e1;
    }
    { MKA8(av, d0, d1) KROUND(av, p0, p1) }       // last tile, no prefetch
#undef KROUND
#undef MKA8
#undef XO

    // dump partial as fp16x2: dword[el*32 + m] = (lo=col m, hi=col 32+m).
    // Slot = blockIdx*4 + wave, 1024 dwords (4 KB). C/D row mapping:
    // el = (rg&3) + 8*(rg>>2) + 4*lh (verified R15-R18).
    unsigned* pdst = partials + ((size_t)blockIdx.x * 4 + wave) * 1024;
#pragma unroll
    for (int rg = 0; rg < 16; ++rg) {
        const int el = (rg & 3) + 8 * (rg >> 2) + 4 * lh;
        union { fp16x2 v; unsigned u; } pk;
        pk.v = __builtin_amdgcn_cvt_pkrtz(accA[rg], accB[rg]);
        pdst[el * 32 + m] = pk.u;
    }
}

// ---------------------------------------------------------------------------
// Tail: sum 4 fp16-packed partials + b1 + ssp -> h1 (LDS) -> layers 2/3 +
// asy + output. Thread (el,g): col c = g*8+j -> dword el*32 + (c mod 32),
// half-select c div 32 (shift = (g>>2)*16, thread-uniform).
// ---------------------------------------------------------------------------
__global__ __launch_bounds__(BLOCK)
void wfnet_tail(const float* __restrict__ rs,
                const float* __restrict__ coords,
                const float* __restrict__ charges,
                const unsigned* __restrict__ partials,
                const float* __restrict__ b1,
                const float* __restrict__ W2,
                const float* __restrict__ b2,
                const float* __restrict__ W3,
                const float* __restrict__ b3,
                float* __restrict__ out)
{
    __shared__ float lds_rs[TB * N_EL * 3];   // 6 KB
    __shared__ float lds_h1[TB * H1LD];       // 8.7 KB

    const int tid = threadIdx.x;
    const int el  = tid >> 3;
    const int g   = tid & 7;
    const int b   = blockIdx.x * TB + el;

    {
        const float* rs_blk = rs + (size_t)blockIdx.x * (TB * N_EL * 3);
        for (int k = tid; k < TB * N_EL * 3; k += BLOCK) lds_rs[k] = rs_blk[k];
    }

    {   // sum 4 fp16 partial slots for (el, cols g*8..g*8+7)
        const unsigned* pb = partials + (size_t)blockIdx.x * 4096
                                      + el * 32 + (g & 3) * 8;
        const int sh = (g >> 2) * 16;
        const float4 ba = ((const float4*)(b1 + g * 8))[0];
        const float4 bb = ((const float4*)(b1 + g * 8))[1];
        float a0 = ba.x, a1 = ba.y, a2 = ba.z, a3 = ba.w;
        float a4 = bb.x, a5 = bb.y, a6 = bb.z, a7 = bb.w;
#pragma unroll
        for (int w = 0; w < 4; ++w) {
            const uint4 q0 = ((const uint4*)(pb + w * 1024))[0];
            const uint4 q1 = ((const uint4*)(pb + w * 1024))[1];
            a0 += unpk(q0.x, sh); a1 += unpk(q0.y, sh);
            a2 += unpk(q0.z, sh); a3 += unpk(q0.w, sh);
            a4 += unpk(q1.x, sh); a5 += unpk(q1.y, sh);
            a6 += unpk(q1.z, sh); a7 += unpk(q1.w, sh);
        }
        float* h1w = lds_h1 + el * H1LD + g * 8;
        h1w[0] = ssp(a0); h1w[1] = ssp(a1); h1w[2] = ssp(a2); h1w[3] = ssp(a3);
        h1w[4] = ssp(a4); h1w[5] = ssp(a5); h1w[6] = ssp(a6); h1w[7] = ssp(a7);
    }

    float asy = 0.0f;
    __syncthreads();
    {
        const float* myrs = lds_rs + el * (N_EL * 3);
        const float4 ch = *(const float4*)charges;
#pragma unroll
        for (int i = 0; i < 8; ++i) {
            const int p = g + 8 * i;
            const int e = p >> 2, n = p & 3;
            const float dx = myrs[e * 3 + 0] - coords[n * 3 + 0];
            const float dy = myrs[e * 3 + 1] - coords[n * 3 + 1];
            const float dz = myrs[e * 3 + 2] - coords[n * 3 + 2];
            const float d = sqrtf(dx * dx + dy * dy + dz * dz);
            const float Z = (n < 2) ? ((n == 0) ? ch.x : ch.y)
                                    : ((n == 2) ? ch.z : ch.w);
            asy += (Z * d + d * d) / (1.0f + d);   // decay = sqrt(2*0.5) = 1
        }
    }
    asy = redg(asy);

    const float4* __restrict__ W2v = (const float4*)W2;
    const float4* __restrict__ b2v = (const float4*)b2;
    const int wbi = g * 2;
    const float4 b2a = b2v[wbi], b2b = b2v[wbi + 1];
    float s0 = b2a.x, s1 = b2a.y, s2 = b2a.z, s3 = b2a.w;
    float s4 = b2b.x, s5 = b2b.y, s6 = b2b.z, s7 = b2b.w;

    const float* __restrict__ h1row = lds_h1 + el * H1LD;
    for (int k = 0; k < HIDDEN; ++k) {
        const float hk  = h1row[k];
        const float4 wa = W2v[k * 16 + wbi];
        const float4 wb = W2v[k * 16 + wbi + 1];
        s0 = fmaf(hk, wa.x, s0); s1 = fmaf(hk, wa.y, s1);
        s2 = fmaf(hk, wa.z, s2); s3 = fmaf(hk, wa.w, s3);
        s4 = fmaf(hk, wb.x, s4); s5 = fmaf(hk, wb.y, s5);
        s6 = fmaf(hk, wb.z, s6); s7 = fmaf(hk, wb.w, s7);
    }

    const float4* __restrict__ W3v = (const float4*)W3;
    const float4 w3a = W3v[wbi], w3b = W3v[wbi + 1];
    float part = ssp(s0) * w3a.x + ssp(s1) * w3a.y
               + ssp(s2) * w3a.z + ssp(s3) * w3a.w
               + ssp(s4) * w3b.x + ssp(s5) * w3b.y
               + ssp(s6) * w3b.z + ssp(s7) * w3b.w;
    part = redg(part);

    if (g == 0) {
        const float ys = part + b3[0];
        out[b] = __expf(ys) * __expf(-asy);
    }
}

extern "C" void kernel_launch(void* const* d_in, const int* in_sizes, int n_in,
                              void* d_out, int out_size, void* d_ws, size_t ws_size,
                              hipStream_t stream) {
    const float* rs      = (const float*)d_in[0];
    const float* coords  = (const float*)d_in[1];
    const float* charges = (const float*)d_in[2];
    const float* W1      = (const float*)d_in[3];
    const float* b1      = (const float*)d_in[4];
    const float* W2      = (const float*)d_in[5];
    const float* b2      = (const float*)d_in[6];
    const float* W3      = (const float*)d_in[7];
    const float* b3      = (const float*)d_in[8];
    float* out = (float*)d_out;

    const int batch = in_sizes[0] / (N_EL * 3);   // 32768
    intx8* w1f8     = (intx8*)d_ws;                             // 368 KB
    float* dists    = (float*)((char*)d_ws + WS_DIST_OFF);      // 24 MB
    unsigned* parts = (unsigned*)((char*)d_ws + WS_PART_OFF);   // 8 MB fp16x2

    prep_w1_kernel<<<N_PAIRS / 2, 256, 0, stream>>>(W1, w1f8);
    dist_kernel<<<batch / TB, 256, 0, stream>>>(rs, coords, dists);
    wfnet_gemm<<<batch / TB, BLOCK, 0, stream>>>(dists, w1f8, parts);
    wfnet_tail<<<batch / TB, BLOCK, 0, stream>>>(rs, coords, charges, parts,
                                                 b1, W2, b2, W3, b3, out);
}

// Round 20
// 157.105 us; speedup vs baseline: 1.0687x; 1.0381x over previous
//
#include <hip/hip_runtime.h>
#include <math.h>

#define N_EL    16
#define N_NUC   4
#define N_FEATS 32
#define N_PAIRS 184
#define HIDDEN  64
#define TB      32           // batch elements per block (one M-tile)
#define BLOCK   256
#define TPW     23           // K-tiles (2 pairs each) per wave; 4*23*2 = 184
#define WS_DIST_OFF 393216   // dists at 384 KB

typedef int   intx8    __attribute__((ext_vector_type(8)));
typedef float floatx16 __attribute__((ext_vector_type(16)));
typedef __fp16 fp16x2  __attribute__((ext_vector_type(2)));

__device__ __forceinline__ float exp2_raw(float x) {
    float r;
    asm("v_exp_f32 %0, %1" : "=v"(r) : "v"(x));
    return r;
}
__device__ __forceinline__ float log2_raw(float x) {
    float r;
    asm("v_log_f32 %0, %1" : "=v"(r) : "v"(x));
    return r;
}
// unpack one half of an fp16x2 dword (shift = 0 or 16, thread-uniform)
__device__ __forceinline__ float unpk(unsigned u, int shift) {
    unsigned short s = (unsigned short)(u >> shift);
    _Float16 h;
    __builtin_memcpy(&h, &s, 2);
    return (float)h;
}

// triu_indices(16, 1)
__constant__ unsigned char c_I[120] = {
    0,0,0,0,0,0,0,0,0,0,0,0,0,0,0,
    1,1,1,1,1,1,1,1,1,1,1,1,1,1,
    2,2,2,2,2,2,2,2,2,2,2,2,2,
    3,3,3,3,3,3,3,3,3,3,3,3,
    4,4,4,4,4,4,4,4,4,4,4,
    5,5,5,5,5,5,5,5,5,5,
    6,6,6,6,6,6,6,6,6,
    7,7,7,7,7,7,7,7,
    8,8,8,8,8,8,8,
    9,9,9,9,9,9,
    10,10,10,10,10,
    11,11,11,11,
    12,12,12,
    13,13,
    14
};
__constant__ unsigned char c_J[120] = {
    1,2,3,4,5,6,7,8,9,10,11,12,13,14,15,
    2,3,4,5,6,7,8,9,10,11,12,13,14,15,
    3,4,5,6,7,8,9,10,11,12,13,14,15,
    4,5,6,7,8,9,10,11,12,13,14,15,
    5,6,7,8,9,10,11,12,13,14,15,
    6,7,8,9,10,11,12,13,14,15,
    7,8,9,10,11,12,13,14,15,
    8,9,10,11,12,13,14,15,
    9,10,11,12,13,14,15,
    10,11,12,13,14,15,
    11,12,13,14,15,
    12,13,14,15,
    13,14,15,
    14,15,
    15
};

// stable ssp on raw HW transcendentals
__device__ __forceinline__ float ssp(float x) {
    const float z = exp2_raw(-fabsf(x) * 1.4426950408889634f);
    const float w = log2_raw(1.0f + z);
    return fmaxf(x, 0.0f) + fmaf(0.6931471805599453f, w, -0.69314718056f);
}
__device__ __forceinline__ float redg(float v) {
    v += __shfl_xor(v, 1);
    v += __shfl_xor(v, 2);
    v += __shfl_xor(v, 4);
    return v;
}

// ---------------------------------------------------------------------------
// Prep (verified R14-R19): W1 -> fp8 e4m3 (pre-scaled 2^6; MFMA applies 2^-6
// via scale_b) in 32x32x64 B-fragment order.
// ---------------------------------------------------------------------------
__global__ __launch_bounds__(256)
void prep_w1_kernel(const float* __restrict__ W1, intx8* __restrict__ ws)
{
    __shared__ float w[2 * N_FEATS * HIDDEN];
    const int t = blockIdx.x;
    const float* src = W1 + (size_t)(2 * t) * (N_FEATS * HIDDEN);
    for (int k = threadIdx.x; k < 2 * N_FEATS * HIDDEN; k += 256) w[k] = src[k];
    __syncthreads();

    const int tid = threadIdx.x;
    if (tid >= 128) return;
    const int lane = tid & 63;
    const int nh   = tid >> 6;
    const int lh   = lane >> 5;
    const int col  = nh * 32 + (lane & 31);
    const int fb   = lh * 16;
    intx8 frag;
#pragma unroll
    for (int r = 0; r < 8; ++r) {
        const int pair = r >> 2;
        const int fo   = fb + ((r & 3) << 2);
        const float v0 = 64.0f * w[(pair * N_FEATS + fo + 0) * 64 + col];
        const float v1 = 64.0f * w[(pair * N_FEATS + fo + 1) * 64 + col];
        const float v2 = 64.0f * w[(pair * N_FEATS + fo + 2) * 64 + col];
        const float v3 = 64.0f * w[(pair * N_FEATS + fo + 3) * 64 + col];
        int d = __builtin_amdgcn_cvt_pk_fp8_f32(v0, v1, 0, false);
        d     = __builtin_amdgcn_cvt_pk_fp8_f32(v2, v3, d, true);
        frag[r] = d;
    }
    ws[(size_t)(t * 2 + nh) * 64 + lane] = frag;
}

// ---------------------------------------------------------------------------
// Dist kernel (R16): all 184 distances per element -> global dw in the exact
// layout the gemm reads: dw[b*5888 + p*32 + el].
// ---------------------------------------------------------------------------
__global__ __launch_bounds__(256)
void dist_kernel(const float* __restrict__ rs,
                 const float* __restrict__ coords,
                 float* __restrict__ dw)
{
    __shared__ float lds_rs[TB * N_EL * 3];   // 6 KB
    const int tid = threadIdx.x;
    {
        const float* rs_blk = rs + (size_t)blockIdx.x * (TB * N_EL * 3);
        for (int k = tid; k < TB * N_EL * 3; k += 256) lds_rs[k] = rs_blk[k];
    }
    __syncthreads();

    const int el = tid & 31, g = tid >> 5;
    const float* myrs = lds_rs + el * (N_EL * 3);
    float* base = dw + (size_t)blockIdx.x * (N_PAIRS * 32) + el;
#pragma unroll
    for (int i = 0; i < 23; ++i) {
        const int p = g + 8 * i;
        float dx, dy, dz;
        if (p < 64) {
            const int e = p >> 2, n = p & 3;
            dx = myrs[e * 3 + 0] - coords[n * 3 + 0];
            dy = myrs[e * 3 + 1] - coords[n * 3 + 1];
            dz = myrs[e * 3 + 2] - coords[n * 3 + 2];
        } else {
            const int q  = p - 64;
            const int ei = 3 * (int)c_I[q], ej = 3 * (int)c_J[q];
            dx = myrs[ei + 0] - myrs[ej + 0];
            dy = myrs[ei + 1] - myrs[ej + 1];
            dz = myrs[ei + 2] - myrs[ej + 2];
        }
        base[p * 32] = sqrtf(dx * dx + dy * dy + dz * dz);
    }
}

// ---------------------------------------------------------------------------
// FUSED gemm + reduction + tail (R20). R19 decode: tail kernel's launch gap
// + partials round trip is the largest attackable term; gemm is
// TLP-saturated. 12 KB LDS (3 fp16 dump slots; slot0 reused in-place as
// fp16 h1 — within-wave in-order LDS makes read-then-overwrite safe) keeps
// 4 blocks/CU, so the gemm keeps its speed while absorbing the tail.
// h1 columns XOR-swizzled by el so tail broadcast reads are conflict-free.
// ---------------------------------------------------------------------------
__global__ __launch_bounds__(BLOCK, 4)
void wfnet_fused(const float* __restrict__ dw,
                 const intx8* __restrict__ ws,
                 const float* __restrict__ coords,
                 const float* __restrict__ charges,
                 const float* __restrict__ b1,
                 const float* __restrict__ W2,
                 const float* __restrict__ b2,
                 const float* __restrict__ W3,
                 const float* __restrict__ b3,
                 float* __restrict__ out)
{
    __shared__ unsigned lds_red[3 * 1024];   // 12 KB; slot0 reused as h1

    const int tid  = threadIdx.x;
    const int wave = tid >> 6;
    const int lane = tid & 63;
    const int m    = lane & 31;
    const int lh   = lane >> 5;
    const int t0   = wave * TPW;
    const int mt   = blockIdx.x;

    const int f0 = lh * 16;
#define MKC(P, FF) float P##1, P##0; { \
    const float fq = (float)(FF) * (1.0f / 31.0f); \
    const float mu = 10.0f * fq * fq; \
    const float is = 7.0f / (1.0f + 10.0f * fq); \
    P##1 = is * 1.2011224087864498f; \
    P##0 = -mu * P##1; }
    MKC(F0_,  f0 + 0)  MKC(F1_,  f0 + 1)  MKC(F2_,  f0 + 2)  MKC(F3_,  f0 + 3)
    MKC(F4_,  f0 + 4)  MKC(F5_,  f0 + 5)  MKC(F6_,  f0 + 6)  MKC(F7_,  f0 + 7)
    MKC(F8_,  f0 + 8)  MKC(F9_,  f0 + 9)  MKC(F10_, f0 + 10) MKC(F11_, f0 + 11)
    MKC(F12_, f0 + 12) MKC(F13_, f0 + 13) MKC(F14_, f0 + 14) MKC(F15_, f0 + 15)
#undef MKC

    floatx16 accA = {};
    floatx16 accB = {};
    const intx8* wq = ws + ((size_t)t0 * 128 + lane);
    const float* dp = dw + (size_t)mt * (N_PAIRS * 32) + t0 * 64 + m;

#define XO(dd, P) ({ const float t_ = fmaf(dd, P##1, P##0); exp2_raw(t_ * -t_); })
#define MKA8(AV, dx0, dx1) \
    intx8 AV; { int dw_; \
    dw_   = __builtin_amdgcn_cvt_pk_fp8_f32(XO(dx0,F0_),  XO(dx0,F1_),  0,  false); \
    AV[0] = __builtin_amdgcn_cvt_pk_fp8_f32(XO(dx0,F2_),  XO(dx0,F3_),  dw_, true); \
    dw_   = __builtin_amdgcn_cvt_pk_fp8_f32(XO(dx0,F4_),  XO(dx0,F5_),  0,  false); \
    AV[1] = __builtin_amdgcn_cvt_pk_fp8_f32(XO(dx0,F6_),  XO(dx0,F7_),  dw_, true); \
    dw_   = __builtin_amdgcn_cvt_pk_fp8_f32(XO(dx0,F8_),  XO(dx0,F9_),  0,  false); \
    AV[2] = __builtin_amdgcn_cvt_pk_fp8_f32(XO(dx0,F10_), XO(dx0,F11_), dw_, true); \
    dw_   = __builtin_amdgcn_cvt_pk_fp8_f32(XO(dx0,F12_), XO(dx0,F13_), 0,  false); \
    AV[3] = __builtin_amdgcn_cvt_pk_fp8_f32(XO(dx0,F14_), XO(dx0,F15_), dw_, true); \
    dw_   = __builtin_amdgcn_cvt_pk_fp8_f32(XO(dx1,F0_),  XO(dx1,F1_),  0,  false); \
    AV[4] = __builtin_amdgcn_cvt_pk_fp8_f32(XO(dx1,F2_),  XO(dx1,F3_),  dw_, true); \
    dw_   = __builtin_amdgcn_cvt_pk_fp8_f32(XO(dx1,F4_),  XO(dx1,F5_),  0,  false); \
    AV[5] = __builtin_amdgcn_cvt_pk_fp8_f32(XO(dx1,F6_),  XO(dx1,F7_),  dw_, true); \
    dw_   = __builtin_amdgcn_cvt_pk_fp8_f32(XO(dx1,F8_),  XO(dx1,F9_),  0,  false); \
    AV[6] = __builtin_amdgcn_cvt_pk_fp8_f32(XO(dx1,F10_), XO(dx1,F11_), dw_, true); \
    dw_   = __builtin_amdgcn_cvt_pk_fp8_f32(XO(dx1,F12_), XO(dx1,F13_), 0,  false); \
    AV[7] = __builtin_amdgcn_cvt_pk_fp8_f32(XO(dx1,F14_), XO(dx1,F15_), dw_, true); }
#define KROUND(AV, Q0, Q1) { \
    accA = __builtin_amdgcn_mfma_scale_f32_32x32x64_f8f6f4( \
               AV, Q0, accA, 0, 0, 0, 0x7F7F7F7F, 0, 0x79797979); \
    accB = __builtin_amdgcn_mfma_scale_f32_32x32x64_f8f6f4( \
               AV, Q1, accB, 0, 0, 0, 0x7F7F7F7F, 0, 0x79797979); }

    intx8 p0 = wq[0], p1 = wq[64];
    float d0 = dp[0], d1 = dp[32];

    for (int t = 0; t < TPW - 1; ++t) {
        const intx8 n0 = wq[128], n1 = wq[192];   // next tile's B-frags
        const float e0 = dp[64],  e1 = dp[96];    // next tile's dists
        MKA8(av, d0, d1)
        KROUND(av, p0, p1)
        wq += 128; dp += 64;
        p0 = n0; p1 = n1; d0 = e0; d1 = e1;
    }
    { MKA8(av, d0, d1) KROUND(av, p0, p1) }       // last tile, no prefetch
#undef KROUND
#undef MKA8
#undef XO

    // ---- reduction: waves 1..3 dump fp16-packed partials (swizzled cols).
    // C/D: col = m (+32 for B), row el = (rg&3)+8*(rg>>2)+4*lh (verified). ----
    if (wave >= 1) {
        unsigned* slot = lds_red + (wave - 1) * 1024;
#pragma unroll
        for (int rg = 0; rg < 16; ++rg) {
            const int el = (rg & 3) + 8 * (rg >> 2) + 4 * lh;
            union { fp16x2 v; unsigned u; } pk;
            pk.v = __builtin_amdgcn_cvt_pkrtz(accA[rg], accB[rg]);
            slot[el * 32 + ((m + el) & 31)] = pk.u;   // XOR-ish swizzle by el
        }
    }
    __syncthreads();
    if (wave == 0) {
        const float bA = b1[m], bB = b1[32 + m];
#pragma unroll
        for (int rg = 0; rg < 16; ++rg) {
            const int el  = (rg & 3) + 8 * (rg >> 2) + 4 * lh;
            const int idx = el * 32 + ((m + el) & 31);
            float a = accA[rg] + bA;
            float c = accB[rg] + bB;
#pragma unroll
            for (int w = 0; w < 3; ++w) {
                const unsigned u = lds_red[w * 1024 + idx];
                a += unpk(u, 0);
                c += unpk(u, 16);
            }
            union { fp16x2 v; unsigned u; } pk;
            pk.v = __builtin_amdgcn_cvt_pkrtz(ssp(a), ssp(c));
            lds_red[idx] = pk.u;   // overwrite slot0 entry read THIS iteration
        }
    }
    __syncthreads();

    // ---- tail: asy (el-nuc dists from dw) + layers 2/3 + output ----
    const int el = tid >> 3;
    const int g  = tid & 7;
    const int b  = mt * TB + el;

    float asy = 0.0f;
    {
        const float4 ch = *(const float4*)charges;
        const float* db = dw + (size_t)mt * (N_PAIRS * 32) + el;
#pragma unroll
        for (int i = 0; i < 8; ++i) {
            const int p = g + 8 * i;
            const float d = db[p * 32];
            const int n = p & 3;
            const float Z = (n < 2) ? ((n == 0) ? ch.x : ch.y)
                                    : ((n == 2) ? ch.z : ch.w);
            asy += (Z * d + d * d) / (1.0f + d);   // decay = sqrt(2*0.5) = 1
        }
    }
    asy = redg(asy);

    const float4* __restrict__ W2v = (const float4*)W2;
    const float4* __restrict__ b2v = (const float4*)b2;
    const int wbi = g * 2;
    const float4 b2a = b2v[wbi], b2b = b2v[wbi + 1];
    float s0 = b2a.x, s1 = b2a.y, s2 = b2a.z, s3 = b2a.w;
    float s4 = b2b.x, s5 = b2b.y, s6 = b2b.z, s7 = b2b.w;

    // h1 col-pair k (cols k, 32+k) at lds_red[el*32 + ((k+el)&31)]
    for (int k = 0; k < 32; ++k) {
        const unsigned u = lds_red[el * 32 + ((k + el) & 31)];
        const float hk0 = unpk(u, 0);
        const float hk1 = unpk(u, 16);
        const float4 wa0 = W2v[k * 16 + wbi];
        const float4 wb0 = W2v[k * 16 + wbi + 1];
        const float4 wa1 = W2v[(32 + k) * 16 + wbi];
        const float4 wb1 = W2v[(32 + k) * 16 + wbi + 1];
        s0 = fmaf(hk0, wa0.x, s0); s1 = fmaf(hk0, wa0.y, s1);
        s2 = fmaf(hk0, wa0.z, s2); s3 = fmaf(hk0, wa0.w, s3);
        s4 = fmaf(hk0, wb0.x, s4); s5 = fmaf(hk0, wb0.y, s5);
        s6 = fmaf(hk0, wb0.z, s6); s7 = fmaf(hk0, wb0.w, s7);
        s0 = fmaf(hk1, wa1.x, s0); s1 = fmaf(hk1, wa1.y, s1);
        s2 = fmaf(hk1, wa1.z, s2); s3 = fmaf(hk1, wa1.w, s3);
        s4 = fmaf(hk1, wb1.x, s4); s5 = fmaf(hk1, wb1.y, s5);
        s6 = fmaf(hk1, wb1.z, s6); s7 = fmaf(hk1, wb1.w, s7);
    }

    const float4* __restrict__ W3v = (const float4*)W3;
    const float4 w3a = W3v[wbi], w3b = W3v[wbi + 1];
    float part = ssp(s0) * w3a.x + ssp(s1) * w3a.y
               + ssp(s2) * w3a.z + ssp(s3) * w3a.w
               + ssp(s4) * w3b.x + ssp(s5) * w3b.y
               + ssp(s6) * w3b.z + ssp(s7) * w3b.w;
    part = redg(part);

    if (g == 0) {
        const float ys = part + b3[0];
        out[b] = __expf(ys) * __expf(-asy);
    }
}

extern "C" void kernel_launch(void* const* d_in, const int* in_sizes, int n_in,
                              void* d_out, int out_size, void* d_ws, size_t ws_size,
                              hipStream_t stream) {
    const float* rs      = (const float*)d_in[0];
    const float* coords  = (const float*)d_in[1];
    const float* charges = (const float*)d_in[2];
    const float* W1      = (const float*)d_in[3];
    const float* b1      = (const float*)d_in[4];
    const float* W2      = (const float*)d_in[5];
    const float* b2      = (const float*)d_in[6];
    const float* W3      = (const float*)d_in[7];
    const float* b3      = (const float*)d_in[8];
    float* out = (float*)d_out;

    const int batch = in_sizes[0] / (N_EL * 3);   // 32768
    intx8* w1f8  = (intx8*)d_ws;                          // 368 KB
    float* dists = (float*)((char*)d_ws + WS_DIST_OFF);   // 24 MB

    prep_w1_kernel<<<N_PAIRS / 2, 256, 0, stream>>>(W1, w1f8);
    dist_kernel<<<batch / TB, 256, 0, stream>>>(rs, coords, dists);
    wfnet_fused<<<batch / TB, BLOCK, 0, stream>>>(dists, w1f8, coords, charges,
                                                  b1, W2, b2, W3, b3, out);
}